// Round 2
// baseline (3195.902 us; speedup 1.0000x reference)
//
#include <hip/hip_runtime.h>
#include <cstdint>

#define GXD 480
#define GYD 360
#define NHD 32
#define NPTS 120000
#define SEGR 129600           // 360*360: ids = x*360+y with x,y in [0,360)
#define NSEG (GXD*GYD)        // 172800
#define EPSB 1e-5f

// ---- bf16 helpers ----
__device__ __forceinline__ float bf2f(unsigned short u) {
    return __uint_as_float(((unsigned int)u) << 16);
}
__device__ __forceinline__ unsigned short f2bf(float f) {
    unsigned int u = __float_as_uint(f);
    u += 0x7fffu + ((u >> 16) & 1u);   // round-to-nearest-even
    return (unsigned short)(u >> 16);
}

// ---- order-preserving float<->uint key for atomicMax segment-max ----
__device__ __forceinline__ unsigned int fkey(float v) {
    unsigned int b = __float_as_uint(v);
    return (b & 0x80000000u) ? ~b : (b | 0x80000000u);
}
__device__ __forceinline__ float funkey(unsigned int k) {
    if (k == 0u) return 0.0f;  // empty (memset) cell -> contributes 0 to E
    unsigned int b = (k & 0x80000000u) ? (k & 0x7fffffffu) : ~k;
    return __uint_as_float(b);
}

// ---- bn0 stats: per-feature sum/sumsq over 120000 points ----
__global__ __launch_bounds__(256) void bn0_stats_kernel(
    const float* __restrict__ fea, float* __restrict__ s0, float* __restrict__ q0)
{
    float s[7] = {0,0,0,0,0,0,0}, q[7] = {0,0,0,0,0,0,0};
    for (int p = blockIdx.x * 256 + threadIdx.x; p < NPTS; p += gridDim.x * 256) {
        const float* r = fea + (size_t)p * 7;
#pragma unroll
        for (int f = 0; f < 7; ++f) { float v = r[f]; s[f] += v; q[f] += v * v; }
    }
    __shared__ float red[256];
    int t = threadIdx.x;
#pragma unroll
    for (int f = 0; f < 7; ++f) {
        red[t] = s[f]; __syncthreads();
        for (int o = 128; o > 0; o >>= 1) {
            if (t < o) red[t] += red[t + o];
            __syncthreads();
        }
        if (t == 0) atomicAdd(&s0[f], red[0]);
        __syncthreads();
        red[t] = q[f]; __syncthreads();
        for (int o = 128; o > 0; o >>= 1) {
            if (t < o) red[t] += red[t + o];
            __syncthreads();
        }
        if (t == 0) atomicAdd(&q0[f], red[0]);
        __syncthreads();
    }
}

// ---- fold bn0 into W1 ----
__global__ void prep0_kernel(const float* __restrict__ s0, const float* __restrict__ q0,
                             const float* __restrict__ g0, const float* __restrict__ b0,
                             const float* __restrict__ W1, const float* __restrict__ b1,
                             float* __restrict__ W1p, float* __restrict__ b1p)
{
    __shared__ float sc[7], sh[7];
    int t = threadIdx.x;
    if (t < 7) {
        float m = s0[t] / (float)NPTS;
        float v = q0[t] / (float)NPTS - m * m;
        float inv = 1.0f / sqrtf(fmaxf(v, 0.f) + EPSB);
        sc[t] = g0[t] * inv;
        sh[t] = b0[t] - m * g0[t] * inv;
    }
    __syncthreads();
    if (t < 64) {
        float acc = b1[t];
#pragma unroll
        for (int f = 0; f < 7; ++f) {
            W1p[f * 64 + t] = W1[f * 64 + t] * sc[f];
            acc += sh[f] * W1[f * 64 + t];
        }
        b1p[t] = acc;
    }
}

// ---- turn column sum/sumsq into bn scale/shift ----
__global__ void prep_bn_kernel(const float* __restrict__ sum, const float* __restrict__ sq,
                               const float* __restrict__ g, const float* __restrict__ b,
                               float* __restrict__ sc, float* __restrict__ sh, int C)
{
    int c = blockIdx.x * blockDim.x + threadIdx.x;
    if (c < C) {
        float m = sum[c] / (float)NPTS;
        float v = sq[c] / (float)NPTS - m * m;
        float inv = 1.0f / sqrtf(fmaxf(v, 0.f) + EPSB);
        sc[c] = g[c] * inv;
        sh[c] = b[c] - m * g[c] * inv;
    }
}

// ---- layer 1: y1(bf16) = fea @ W1' + b1' (K=7, Nc=64), + fp32 col stats ----
__global__ __launch_bounds__(256) void layer1_kernel(
    const float* __restrict__ fea, const float* __restrict__ W1p, const float* __restrict__ b1p,
    unsigned short* __restrict__ y1, float* __restrict__ sum1, float* __restrict__ sq1)
{
    __shared__ float Wl[448], bl[64], feaL[448];
    __shared__ float red[4][64];
    int t = threadIdx.x;
    int p0 = blockIdx.x * 64;
    for (int i = t; i < 448; i += 256) { Wl[i] = W1p[i]; feaL[i] = fea[(size_t)p0 * 7 + i]; }
    if (t < 64) bl[t] = b1p[t];
    __syncthreads();
    int c = t & 63, pr = t >> 6;
    float s = 0.f, q = 0.f;
#pragma unroll
    for (int it = 0; it < 16; ++it) {
        int pl = it * 4 + pr;
        float v = bl[c];
#pragma unroll
        for (int f = 0; f < 7; ++f) v = fmaf(feaL[pl * 7 + f], Wl[f * 64 + c], v);
        y1[(size_t)(p0 + pl) * 64 + c] = f2bf(v);
        s += v; q += v * v;
    }
    red[pr][c] = s; __syncthreads();
    if (t < 64) atomicAdd(&sum1[c], red[0][c] + red[1][c] + red[2][c] + red[3][c]);
    __syncthreads();
    red[pr][c] = q; __syncthreads();
    if (t < 64) atomicAdd(&sq1[c], red[0][c] + red[1][c] + red[2][c] + red[3][c]);
}

// ---- mid GEMM: Y(bf16) = relu(A(bf16)*sc+sh) @ W + bias, + fp32 col stats ----
// 64x64 tile, 256 threads, 4x4 microtile, K-step 16
template<int K>
__global__ __launch_bounds__(256) void gemm_bn_kernel(
    const unsigned short* __restrict__ A, const float* __restrict__ scale,
    const float* __restrict__ shift, const float* __restrict__ W,
    const float* __restrict__ bias, unsigned short* __restrict__ Y,
    float* __restrict__ osum, float* __restrict__ osq, int Nc)
{
    __shared__ float As[16][72];   // 72*4B = 18*16B: float4-aligned rows
    __shared__ float Bs[16][64];
    __shared__ float scs[K], shs[K];
    __shared__ float red[16][64];
    int t = threadIdx.x;
    int tx = t & 15, ty = t >> 4;
    int m0 = blockIdx.x * 64, c0 = blockIdx.y * 64;
    for (int i = t; i < K; i += 256) { scs[i] = scale[i]; shs[i] = shift[i]; }
    const int arow = t >> 2, akq = (t & 3) * 4;
    const int bkk = t >> 4, bcc = (t & 15) * 4;
    float acc[4][4] = {};
    for (int kt = 0; kt < K; kt += 16) {
        __syncthreads();
        ushort4 av = *(const ushort4*)(A + (size_t)(m0 + arow) * K + kt + akq);
        As[akq + 0][arow] = fmaxf(fmaf(bf2f(av.x), scs[kt + akq + 0], shs[kt + akq + 0]), 0.f);
        As[akq + 1][arow] = fmaxf(fmaf(bf2f(av.y), scs[kt + akq + 1], shs[kt + akq + 1]), 0.f);
        As[akq + 2][arow] = fmaxf(fmaf(bf2f(av.z), scs[kt + akq + 2], shs[kt + akq + 2]), 0.f);
        As[akq + 3][arow] = fmaxf(fmaf(bf2f(av.w), scs[kt + akq + 3], shs[kt + akq + 3]), 0.f);
        *(float4*)&Bs[bkk][bcc] = *(const float4*)(W + (size_t)(kt + bkk) * Nc + c0 + bcc);
        __syncthreads();
#pragma unroll
        for (int kk = 0; kk < 16; ++kk) {
            float4 a = *(const float4*)&As[kk][ty * 4];
            float4 bq = *(const float4*)&Bs[kk][tx * 4];
            acc[0][0] = fmaf(a.x, bq.x, acc[0][0]); acc[0][1] = fmaf(a.x, bq.y, acc[0][1]);
            acc[0][2] = fmaf(a.x, bq.z, acc[0][2]); acc[0][3] = fmaf(a.x, bq.w, acc[0][3]);
            acc[1][0] = fmaf(a.y, bq.x, acc[1][0]); acc[1][1] = fmaf(a.y, bq.y, acc[1][1]);
            acc[1][2] = fmaf(a.y, bq.z, acc[1][2]); acc[1][3] = fmaf(a.y, bq.w, acc[1][3]);
            acc[2][0] = fmaf(a.z, bq.x, acc[2][0]); acc[2][1] = fmaf(a.z, bq.y, acc[2][1]);
            acc[2][2] = fmaf(a.z, bq.z, acc[2][2]); acc[2][3] = fmaf(a.z, bq.w, acc[2][3]);
            acc[3][0] = fmaf(a.w, bq.x, acc[3][0]); acc[3][1] = fmaf(a.w, bq.y, acc[3][1]);
            acc[3][2] = fmaf(a.w, bq.z, acc[3][2]); acc[3][3] = fmaf(a.w, bq.w, acc[3][3]);
        }
    }
    float4 bv = *(const float4*)(bias + c0 + tx * 4);
#pragma unroll
    for (int i = 0; i < 4; ++i) {
        acc[i][0] += bv.x; acc[i][1] += bv.y; acc[i][2] += bv.z; acc[i][3] += bv.w;
        ushort4 yv;
        yv.x = f2bf(acc[i][0]); yv.y = f2bf(acc[i][1]);
        yv.z = f2bf(acc[i][2]); yv.w = f2bf(acc[i][3]);
        *(ushort4*)(Y + (size_t)(m0 + ty * 4 + i) * Nc + c0 + tx * 4) = yv;
    }
    __syncthreads();
#pragma unroll
    for (int j = 0; j < 4; ++j)
        red[ty][tx * 4 + j] = acc[0][j] + acc[1][j] + acc[2][j] + acc[3][j];
    __syncthreads();
    if (t < 64) {
        float s = 0.f;
#pragma unroll
        for (int r = 0; r < 16; ++r) s += red[r][t];
        atomicAdd(&osum[c0 + t], s);
    }
    __syncthreads();
#pragma unroll
    for (int j = 0; j < 4; ++j)
        red[ty][tx * 4 + j] = acc[0][j]*acc[0][j] + acc[1][j]*acc[1][j]
                            + acc[2][j]*acc[2][j] + acc[3][j]*acc[3][j];
    __syncthreads();
    if (t < 64) {
        float s = 0.f;
#pragma unroll
        for (int r = 0; r < 16; ++r) s += red[r][t];
        atomicAdd(&osq[c0 + t], s);
    }
}

// ---- L4 column-group scatter: y4[:, g*CG:(g+1)*CG] -> atomicMax keys D[cell][CG] ----
template<int CG>
__global__ __launch_bounds__(256) void scatter_kernel(
    const unsigned short* __restrict__ A, const float* __restrict__ scale,
    const float* __restrict__ shift, const float* __restrict__ W4,
    const float* __restrict__ b4, const int* __restrict__ xy,
    int g, unsigned int* __restrict__ D)
{
    constexpr int K = 256;
    constexpr int TX = CG / 4;        // threads across cols (4 cols each)
    constexpr int TYN = 256 / TX;     // threads across rows
    constexpr int RPT = 64 / TYN;     // rows per thread
    __shared__ float As[16][72];
    __shared__ float Bs[16][CG];
    __shared__ float scs[256], shs[256];
    __shared__ int ids_s[64];
    int t = threadIdx.x;
    int m0 = blockIdx.x * 64;
    int c0 = g * CG;
    for (int i = t; i < 256; i += 256) { scs[i] = scale[i]; shs[i] = shift[i]; }
    if (t < 64) {
        int p = m0 + t;
        ids_s[t] = xy[(size_t)p * 2] * GYD + xy[(size_t)p * 2 + 1];
    }
    const int arow = t >> 2, akq = (t & 3) * 4;
    const int tx = t % TX, ty = t / TX;
    float acc[RPT][4] = {};
    for (int kt = 0; kt < K; kt += 16) {
        __syncthreads();
        ushort4 av = *(const ushort4*)(A + (size_t)(m0 + arow) * K + kt + akq);
        As[akq + 0][arow] = fmaxf(fmaf(bf2f(av.x), scs[kt + akq + 0], shs[kt + akq + 0]), 0.f);
        As[akq + 1][arow] = fmaxf(fmaf(bf2f(av.y), scs[kt + akq + 1], shs[kt + akq + 1]), 0.f);
        As[akq + 2][arow] = fmaxf(fmaf(bf2f(av.z), scs[kt + akq + 2], shs[kt + akq + 2]), 0.f);
        As[akq + 3][arow] = fmaxf(fmaf(bf2f(av.w), scs[kt + akq + 3], shs[kt + akq + 3]), 0.f);
        if constexpr (CG == 64) {
            int bkk = t >> 4, bcc = (t & 15) * 4;
            *(float4*)&Bs[bkk][bcc] = *(const float4*)(W4 + (size_t)(kt + bkk) * 512 + c0 + bcc);
        } else {
            if (t < 128) {
                int bkk = t >> 3, bcc = (t & 7) * 4;
                *(float4*)&Bs[bkk][bcc] = *(const float4*)(W4 + (size_t)(kt + bkk) * 512 + c0 + bcc);
            }
        }
        __syncthreads();
#pragma unroll
        for (int kk = 0; kk < 16; ++kk) {
            float4 bq = *(const float4*)&Bs[kk][tx * 4];
            if constexpr (RPT == 4) {
                float4 a = *(const float4*)&As[kk][ty * 4];
                acc[0][0] = fmaf(a.x, bq.x, acc[0][0]); acc[0][1] = fmaf(a.x, bq.y, acc[0][1]);
                acc[0][2] = fmaf(a.x, bq.z, acc[0][2]); acc[0][3] = fmaf(a.x, bq.w, acc[0][3]);
                acc[1][0] = fmaf(a.y, bq.x, acc[1][0]); acc[1][1] = fmaf(a.y, bq.y, acc[1][1]);
                acc[1][2] = fmaf(a.y, bq.z, acc[1][2]); acc[1][3] = fmaf(a.y, bq.w, acc[1][3]);
                acc[2][0] = fmaf(a.z, bq.x, acc[2][0]); acc[2][1] = fmaf(a.z, bq.y, acc[2][1]);
                acc[2][2] = fmaf(a.z, bq.z, acc[2][2]); acc[2][3] = fmaf(a.z, bq.w, acc[2][3]);
                acc[3][0] = fmaf(a.w, bq.x, acc[3][0]); acc[3][1] = fmaf(a.w, bq.y, acc[3][1]);
                acc[3][2] = fmaf(a.w, bq.z, acc[3][2]); acc[3][3] = fmaf(a.w, bq.w, acc[3][3]);
            } else {
                float2 a = *(const float2*)&As[kk][ty * 2];
                acc[0][0] = fmaf(a.x, bq.x, acc[0][0]); acc[0][1] = fmaf(a.x, bq.y, acc[0][1]);
                acc[0][2] = fmaf(a.x, bq.z, acc[0][2]); acc[0][3] = fmaf(a.x, bq.w, acc[0][3]);
                acc[1][0] = fmaf(a.y, bq.x, acc[1][0]); acc[1][1] = fmaf(a.y, bq.y, acc[1][1]);
                acc[1][2] = fmaf(a.y, bq.z, acc[1][2]); acc[1][3] = fmaf(a.y, bq.w, acc[1][3]);
            }
        }
    }
    float4 bv = *(const float4*)(b4 + c0 + tx * 4);
#pragma unroll
    for (int r = 0; r < RPT; ++r) {
        unsigned int id = (unsigned int)ids_s[ty * RPT + r];
        unsigned int* rp = D + (size_t)id * CG + tx * 4;
        atomicMax(&rp[0], fkey(acc[r][0] + bv.x));
        atomicMax(&rp[1], fkey(acc[r][1] + bv.y));
        atomicMax(&rp[2], fkey(acc[r][2] + bv.z));
        atomicMax(&rp[3], fkey(acc[r][3] + bv.w));
    }
}

// ---- accumulate E[cell][32] += funkey(D[cell][:CG]) @ W5[g*CG:(g+1)*CG, :] ----
template<int CG>
__global__ __launch_bounds__(256) void accum_kernel(
    const unsigned int* __restrict__ D, const float* __restrict__ W5,
    int g, float* __restrict__ E)
{
    __shared__ float Ds[64][CG + 1];
    __shared__ float W5s[CG][32];
    int t = threadIdx.x;
    int c0 = blockIdx.x * 64;     // cell base (grid = SEGR/64)
    for (int i = t; i < CG * 32; i += 256) {
        int k = i >> 5, c = i & 31;
        W5s[k][c] = W5[(size_t)(g * CG + k) * 32 + c];
    }
    constexpr int QPC = CG / 4;   // uint4 loads per cell row
    for (int i = t; i < 64 * QPC; i += 256) {
        int cell = i / QPC, kq = (i % QPC) * 4;
        uint4 v = *(const uint4*)(D + (size_t)(c0 + cell) * CG + kq);
        Ds[cell][kq + 0] = funkey(v.x);
        Ds[cell][kq + 1] = funkey(v.y);
        Ds[cell][kq + 2] = funkey(v.z);
        Ds[cell][kq + 3] = funkey(v.w);
    }
    __syncthreads();
    int cl = t & 63, og = t >> 6;
    float acc[8] = {};
#pragma unroll 8
    for (int k = 0; k < CG; ++k) {
        float v = Ds[cl][k];
#pragma unroll
        for (int j = 0; j < 8; ++j) acc[j] = fmaf(v, W5s[k][og * 8 + j], acc[j]);
    }
    float* e = E + (size_t)(c0 + cl) * 32 + og * 8;
    float4 e0 = *(float4*)e, e1 = *(float4*)(e + 4);
    e0.x += acc[0]; e0.y += acc[1]; e0.z += acc[2]; e0.w += acc[3];
    e1.x += acc[4]; e1.y += acc[5]; e1.z += acc[6]; e1.w += acc[7];
    *(float4*)e = e0; *(float4*)(e + 4) = e1;
}

// ---- occupancy scatter ----
__global__ __launch_bounds__(256) void occ_kernel(const int* __restrict__ xy,
                                                  unsigned char* __restrict__ occ)
{
    int p = blockIdx.x * 256 + threadIdx.x;
    if (p < NPTS) {
        int id = xy[(size_t)p * 2] * GYD + xy[(size_t)p * 2 + 1];
        occ[id] = 1;
    }
}

// ---- output: out[h][cell] = occ ? relu(E[cell][h] + b5[h]) : 0; zeros for gx>=360 ----
__global__ __launch_bounds__(256) void out_kernel(
    const float* __restrict__ E, const unsigned char* __restrict__ occ,
    const float* __restrict__ b5, float* __restrict__ out)
{
    int t = threadIdx.x;
    int c0 = blockIdx.x * 64;
    int lane = t & 63, hq = t >> 6;     // hq in [0,4): handles h = hq*8 .. hq*8+7
    int cell = c0 + lane;
    if (c0 >= SEGR) {
#pragma unroll
        for (int j = 0; j < 8; ++j)
            out[(size_t)(hq * 8 + j) * NSEG + cell] = 0.f;
        return;
    }
    bool oc = occ[cell] != 0;
    float4 e0 = *(const float4*)(E + (size_t)cell * 32 + hq * 8);
    float4 e1 = *(const float4*)(E + (size_t)cell * 32 + hq * 8 + 4);
    float r[8] = {e0.x, e0.y, e0.z, e0.w, e1.x, e1.y, e1.z, e1.w};
#pragma unroll
    for (int j = 0; j < 8; ++j) {
        float v = oc ? fmaxf(r[j] + b5[hq * 8 + j], 0.f) : 0.f;
        out[(size_t)(hq * 8 + j) * NSEG + cell] = v;
    }
}

extern "C" void kernel_launch(void* const* d_in, const int* in_sizes, int n_in,
                              void* d_out, int out_size, void* d_ws, size_t ws_size,
                              hipStream_t stream)
{
    const float* pt_fea = (const float*)d_in[0];
    const int*   xy_ind = (const int*)d_in[1];
    const float* bn0_g  = (const float*)d_in[2];
    const float* bn0_b  = (const float*)d_in[3];
    const float* W1     = (const float*)d_in[4];
    const float* b1     = (const float*)d_in[5];
    const float* bn1_g  = (const float*)d_in[6];
    const float* bn1_b  = (const float*)d_in[7];
    const float* W2     = (const float*)d_in[8];
    const float* b2     = (const float*)d_in[9];
    const float* bn2_g  = (const float*)d_in[10];
    const float* bn2_b  = (const float*)d_in[11];
    const float* W3     = (const float*)d_in[12];
    const float* b3     = (const float*)d_in[13];
    const float* bn3_g  = (const float*)d_in[14];
    const float* bn3_b  = (const float*)d_in[15];
    const float* W4     = (const float*)d_in[16];
    const float* b4     = (const float*)d_in[17];
    const float* W5     = (const float*)d_in[18];
    const float* b5     = (const float*)d_in[19];
    float* out = (float*)d_out;

    // ---- workspace layout (bytes), region-reusing; adaptive to ws_size ----
    // [0, 61.44M):   y3 bf16 (written L3); y1 bf16 [0,15.36M) lives here earlier (dead before L3)
    // [61.44M, 92.16M): y2 bf16 (dead after L3); reused as D keys during scatter phase
    // [61.44M+Dsz, +16.59M): E accumulator
    // tail: stats (16KB) + occ bytes
    const bool big = ws_size >= (size_t)113 * 1024 * 1024;
    const int CG = big ? 64 : 32;                 // L4/L5 column-group width
    const size_t oY3 = 0;
    const size_t oY1 = 0;                          // overlaps y3 region (safe)
    const size_t oY2 = 61440000;                   // 120000*256*2
    const size_t oD  = 61440000;                   // reuses y2 region (+ beyond for CG=64)
    const size_t Dsz = (size_t)SEGR * CG * 4;
    const size_t oE  = oD + Dsz;
    const size_t oS  = oE + (size_t)SEGR * 32 * 4;
    const size_t oOc = oS + 4096 * 4;

    unsigned short* y1 = (unsigned short*)((char*)d_ws + oY1);
    unsigned short* y2 = (unsigned short*)((char*)d_ws + oY2);
    unsigned short* y3 = (unsigned short*)((char*)d_ws + oY3);
    unsigned int*   D  = (unsigned int*)((char*)d_ws + oD);
    float*          E  = (float*)((char*)d_ws + oE);
    float*          st = (float*)((char*)d_ws + oS);
    unsigned char* occ = (unsigned char*)((char*)d_ws + oOc);

    float* s0 = st + 0;     float* q0 = st + 8;
    float* W1p = st + 16;   float* b1p = st + 464;
    float* sum1 = st + 528; float* sq1 = st + 592; float* sc1 = st + 656; float* sh1 = st + 720;
    float* sum2 = st + 784; float* sq2 = st + 912; float* sc2 = st + 1040; float* sh2 = st + 1168;
    float* sum3 = st + 1296; float* sq3 = st + 1552; float* sc3 = st + 1808; float* sh3 = st + 2064;

    const int ngroups = 512 / CG;

    for (int b = 0; b < 2; ++b) {
        const float* fea_b = pt_fea + (size_t)b * NPTS * 7;
        const int*   xy_b  = xy_ind + (size_t)b * NPTS * 2;
        float*       out_b = out + (size_t)b * NHD * NSEG;

        (void)hipMemsetAsync(st, 0, 2320 * sizeof(float), stream);
        (void)hipMemsetAsync(occ, 0, SEGR, stream);
        (void)hipMemsetAsync(E, 0, (size_t)SEGR * 32 * sizeof(float), stream);

        bn0_stats_kernel<<<128, 256, 0, stream>>>(fea_b, s0, q0);
        prep0_kernel<<<1, 64, 0, stream>>>(s0, q0, bn0_g, bn0_b, W1, b1, W1p, b1p);
        layer1_kernel<<<NPTS / 64, 256, 0, stream>>>(fea_b, W1p, b1p, y1, sum1, sq1);
        prep_bn_kernel<<<1, 64, 0, stream>>>(sum1, sq1, bn1_g, bn1_b, sc1, sh1, 64);
        gemm_bn_kernel<64><<<dim3(NPTS / 64, 2), 256, 0, stream>>>(
            y1, sc1, sh1, W2, b2, y2, sum2, sq2, 128);
        prep_bn_kernel<<<1, 128, 0, stream>>>(sum2, sq2, bn2_g, bn2_b, sc2, sh2, 128);
        gemm_bn_kernel<128><<<dim3(NPTS / 64, 4), 256, 0, stream>>>(
            y2, sc2, sh2, W3, b3, y3, sum3, sq3, 256);
        prep_bn_kernel<<<1, 256, 0, stream>>>(sum3, sq3, bn3_g, bn3_b, sc3, sh3, 256);
        occ_kernel<<<(NPTS + 255) / 256, 256, 0, stream>>>(xy_b, occ);

        for (int g = 0; g < ngroups; ++g) {
            (void)hipMemsetAsync(D, 0, Dsz, stream);
            if (CG == 64) {
                scatter_kernel<64><<<NPTS / 64, 256, 0, stream>>>(
                    y3, sc3, sh3, W4, b4, xy_b, g, D);
                accum_kernel<64><<<SEGR / 64, 256, 0, stream>>>(D, W5, g, E);
            } else {
                scatter_kernel<32><<<NPTS / 64, 256, 0, stream>>>(
                    y3, sc3, sh3, W4, b4, xy_b, g, D);
                accum_kernel<32><<<SEGR / 64, 256, 0, stream>>>(D, W5, g, E);
            }
        }
        out_kernel<<<NSEG / 64, 256, 0, stream>>>(E, occ, b5, out_b);
    }
}

// Round 3
// 1558.806 us; speedup vs baseline: 2.0502x; 2.0502x over previous
//
#include <hip/hip_runtime.h>
#include <cstdint>

#define GXD 480
#define GYD 360
#define NHD 32
#define NPTS 120000
#define SEGR 129600           // 360*360: ids = x*360+y with x,y in [0,360)
#define NSEG (GXD*GYD)        // 172800
#define EPSB 1e-5f

using short8 = __attribute__((ext_vector_type(8))) short;   // 8 bf16 in 4 VGPRs
using f32x4  = __attribute__((ext_vector_type(4))) float;   // MFMA accumulator

// ---- bf16 helpers ----
__device__ __forceinline__ float bf2f(unsigned short u) {
    return __uint_as_float(((unsigned int)u) << 16);
}
__device__ __forceinline__ unsigned short f2bf(float f) {
    unsigned int u = __float_as_uint(f);
    u += 0x7fffu + ((u >> 16) & 1u);   // round-to-nearest-even
    return (unsigned short)(u >> 16);
}

// ---- order-preserving float<->uint key for atomicMax segment-max ----
__device__ __forceinline__ unsigned int fkey(float v) {
    unsigned int b = __float_as_uint(v);
    return (b & 0x80000000u) ? ~b : (b | 0x80000000u);
}
__device__ __forceinline__ float funkey(unsigned int k) {
    if (k == 0u) return 0.0f;  // empty (memset) cell -> contributes 0 to E
    unsigned int b = (k & 0x80000000u) ? (k & 0x7fffffffu) : ~k;
    return __uint_as_float(b);
}

// ---- staging helper: load 8 bf16, apply bn(scale,shift)+relu, store 16B to LDS ----
__device__ __forceinline__ void bn_stage8(const unsigned short* gp, const float* scs,
                                          const float* shs, int kbase,
                                          unsigned short* lp, bool valid)
{
    if (valid) {
        uint4 raw = *(const uint4*)gp;
        unsigned int wds[4] = {raw.x, raw.y, raw.z, raw.w};
        unsigned int ow[4];
#pragma unroll
        for (int q = 0; q < 4; ++q) {
            float lo = bf2f((unsigned short)(wds[q] & 0xffffu));
            float hi = bf2f((unsigned short)(wds[q] >> 16));
            lo = fmaxf(fmaf(lo, scs[kbase + 2*q + 0], shs[kbase + 2*q + 0]), 0.f);
            hi = fmaxf(fmaf(hi, scs[kbase + 2*q + 1], shs[kbase + 2*q + 1]), 0.f);
            ow[q] = (unsigned int)f2bf(lo) | ((unsigned int)f2bf(hi) << 16);
        }
        *(uint4*)lp = make_uint4(ow[0], ow[1], ow[2], ow[3]);
    } else {
        *(uint4*)lp = make_uint4(0u, 0u, 0u, 0u);
    }
}

// ---- bn0 stats: per-feature sum/sumsq over 120000 points ----
__global__ __launch_bounds__(256) void bn0_stats_kernel(
    const float* __restrict__ fea, float* __restrict__ s0, float* __restrict__ q0)
{
    float s[7] = {0,0,0,0,0,0,0}, q[7] = {0,0,0,0,0,0,0};
    for (int p = blockIdx.x * 256 + threadIdx.x; p < NPTS; p += gridDim.x * 256) {
        const float* r = fea + (size_t)p * 7;
#pragma unroll
        for (int f = 0; f < 7; ++f) { float v = r[f]; s[f] += v; q[f] += v * v; }
    }
    __shared__ float red[256];
    int t = threadIdx.x;
#pragma unroll
    for (int f = 0; f < 7; ++f) {
        red[t] = s[f]; __syncthreads();
        for (int o = 128; o > 0; o >>= 1) {
            if (t < o) red[t] += red[t + o];
            __syncthreads();
        }
        if (t == 0) atomicAdd(&s0[f], red[0]);
        __syncthreads();
        red[t] = q[f]; __syncthreads();
        for (int o = 128; o > 0; o >>= 1) {
            if (t < o) red[t] += red[t + o];
            __syncthreads();
        }
        if (t == 0) atomicAdd(&q0[f], red[0]);
        __syncthreads();
    }
}

// ---- fold bn0 into W1 ----
__global__ void prep0_kernel(const float* __restrict__ s0, const float* __restrict__ q0,
                             const float* __restrict__ g0, const float* __restrict__ b0,
                             const float* __restrict__ W1, const float* __restrict__ b1,
                             float* __restrict__ W1p, float* __restrict__ b1p)
{
    __shared__ float sc[7], sh[7];
    int t = threadIdx.x;
    if (t < 7) {
        float m = s0[t] / (float)NPTS;
        float v = q0[t] / (float)NPTS - m * m;
        float inv = 1.0f / sqrtf(fmaxf(v, 0.f) + EPSB);
        sc[t] = g0[t] * inv;
        sh[t] = b0[t] - m * g0[t] * inv;
    }
    __syncthreads();
    if (t < 64) {
        float acc = b1[t];
#pragma unroll
        for (int f = 0; f < 7; ++f) {
            W1p[f * 64 + t] = W1[f * 64 + t] * sc[f];
            acc += sh[f] * W1[f * 64 + t];
        }
        b1p[t] = acc;
    }
}

// ---- turn column sum/sumsq into bn scale/shift ----
__global__ void prep_bn_kernel(const float* __restrict__ sum, const float* __restrict__ sq,
                               const float* __restrict__ g, const float* __restrict__ b,
                               float* __restrict__ sc, float* __restrict__ sh, int C)
{
    int c = blockIdx.x * blockDim.x + threadIdx.x;
    if (c < C) {
        float m = sum[c] / (float)NPTS;
        float v = sq[c] / (float)NPTS - m * m;
        float inv = 1.0f / sqrtf(fmaxf(v, 0.f) + EPSB);
        sc[c] = g[c] * inv;
        sh[c] = b[c] - m * g[c] * inv;
    }
}

// ---- weight transpose+cast: Wt[n][k] = bf16(W[k][n]) ----
__global__ __launch_bounds__(256) void wtrans_kernel(const float* __restrict__ W,
                                                     unsigned short* __restrict__ Wt,
                                                     int K, int N)
{
    int i = blockIdx.x * 256 + threadIdx.x;
    if (i < K * N) {
        int k = i / N, n = i % N;
        Wt[(size_t)n * K + k] = f2bf(W[i]);
    }
}

// ---- layer 1: y1(bf16) = fea @ W1' + b1' (K=7, Nc=64), + fp32 col stats ----
__global__ __launch_bounds__(256) void layer1_kernel(
    const float* __restrict__ fea, const float* __restrict__ W1p, const float* __restrict__ b1p,
    unsigned short* __restrict__ y1, float* __restrict__ sum1, float* __restrict__ sq1)
{
    __shared__ float Wl[448], bl[64], feaL[448];
    __shared__ float red[4][64];
    int t = threadIdx.x;
    int p0 = blockIdx.x * 64;
    for (int i = t; i < 448; i += 256) { Wl[i] = W1p[i]; feaL[i] = fea[(size_t)p0 * 7 + i]; }
    if (t < 64) bl[t] = b1p[t];
    __syncthreads();
    int c = t & 63, pr = t >> 6;
    float s = 0.f, q = 0.f;
#pragma unroll
    for (int it = 0; it < 16; ++it) {
        int pl = it * 4 + pr;
        float v = bl[c];
#pragma unroll
        for (int f = 0; f < 7; ++f) v = fmaf(feaL[pl * 7 + f], Wl[f * 64 + c], v);
        y1[(size_t)(p0 + pl) * 64 + c] = f2bf(v);
        s += v; q += v * v;
    }
    red[pr][c] = s; __syncthreads();
    if (t < 64) atomicAdd(&sum1[c], red[0][c] + red[1][c] + red[2][c] + red[3][c]);
    __syncthreads();
    red[pr][c] = q; __syncthreads();
    if (t < 64) atomicAdd(&sq1[c], red[0][c] + red[1][c] + red[2][c] + red[3][c]);
}

// ---- MFMA mid GEMM: Y(bf16) = relu(A*sc+sh) @ W + bias, + fp32 col stats ----
// 128x128 tile, 4 waves in 2x2, each wave 64x64 via 4x4 mfma_16x16x32_bf16 frags
template<int K, int NC>
__global__ __launch_bounds__(256) void gemm_bn_mfma(
    const unsigned short* __restrict__ A, const float* __restrict__ scale,
    const float* __restrict__ shift, const unsigned short* __restrict__ Wt,
    const float* __restrict__ bias, unsigned short* __restrict__ Y,
    float* __restrict__ osum, float* __restrict__ osq)
{
    __shared__ __align__(16) unsigned short As[128 * 40];  // stride 40 ushorts (80B)
    __shared__ __align__(16) unsigned short Bs[128 * 40];
    __shared__ float scs[K], shs[K];
    __shared__ float bcols[128], colsum[128], colsq[128];
    int t = threadIdx.x;
    int m0 = blockIdx.x * 128, c0 = blockIdx.y * 128;
    for (int i = t; i < K; i += 256) { scs[i] = scale[i]; shs[i] = shift[i]; }
    if (t < 128) { bcols[t] = bias[c0 + t]; colsum[t] = 0.f; colsq[t] = 0.f; }
    int lane = t & 63, w = t >> 6, quad = lane >> 4, lr = lane & 15;
    int wr = w >> 1, wc = w & 1;
    f32x4 acc[4][4];
#pragma unroll
    for (int i = 0; i < 4; ++i)
#pragma unroll
        for (int j = 0; j < 4; ++j) acc[i][j] = (f32x4){0.f, 0.f, 0.f, 0.f};

    for (int kt = 0; kt < K; kt += 32) {
        __syncthreads();
#pragma unroll
        for (int i = 0; i < 2; ++i) {          // A tile: 128 rows x 32 k
            int cch = t + i * 256;
            int row = cch >> 2, ko = (cch & 3) * 8;
            int gr = m0 + row;
            bn_stage8(A + (size_t)gr * K + kt + ko, scs, shs, kt + ko,
                      &As[row * 40 + ko], gr < NPTS);
        }
#pragma unroll
        for (int i = 0; i < 2; ++i) {          // B tile: 128 n x 32 k (from Wt[n][k])
            int cch = t + i * 256;
            int n = cch >> 2, ko = (cch & 3) * 8;
            *(uint4*)&Bs[n * 40 + ko] = *(const uint4*)(Wt + (size_t)(c0 + n) * K + kt + ko);
        }
        __syncthreads();
        short8 af[4], bfr[4];
#pragma unroll
        for (int mi = 0; mi < 4; ++mi)
            af[mi] = *(const short8*)&As[(wr * 64 + mi * 16 + lr) * 40 + quad * 8];
#pragma unroll
        for (int ni = 0; ni < 4; ++ni)
            bfr[ni] = *(const short8*)&Bs[(wc * 64 + ni * 16 + lr) * 40 + quad * 8];
#pragma unroll
        for (int mi = 0; mi < 4; ++mi)
#pragma unroll
            for (int ni = 0; ni < 4; ++ni)
                acc[mi][ni] = __builtin_amdgcn_mfma_f32_16x16x32_bf16(
                    af[mi], bfr[ni], acc[mi][ni], 0, 0, 0);
    }
    // epilogue: bias, store bf16, column stats (C/D layout: col=lane&15, row=quad*4+reg)
#pragma unroll
    for (int ni = 0; ni < 4; ++ni) {
        int col = wc * 64 + ni * 16 + lr;
        float bv = bcols[col];
        float s = 0.f, q = 0.f;
#pragma unroll
        for (int mi = 0; mi < 4; ++mi) {
            int rb = wr * 64 + mi * 16 + quad * 4;
#pragma unroll
            for (int r = 0; r < 4; ++r) {
                int grow = m0 + rb + r;
                if (grow < NPTS) {
                    float v = acc[mi][ni][r] + bv;
                    Y[(size_t)grow * NC + c0 + col] = f2bf(v);
                    s += v; q += v * v;
                }
            }
        }
        atomicAdd(&colsum[col], s);
        atomicAdd(&colsq[col], q);
    }
    __syncthreads();
    if (t < 128) {
        atomicAdd(&osum[c0 + t], colsum[t]);
        atomicAdd(&osq[c0 + t], colsq[t]);
    }
}

// ---- MFMA L4 scatter: y4[:, g*CG:(g+1)*CG] -> atomicMax keys D[cell][CG] ----
// 128xCG tile, 4 waves each 32 rows x CG cols
template<int CG>
__global__ __launch_bounds__(256) void scatter_mfma(
    const unsigned short* __restrict__ A, const float* __restrict__ scale,
    const float* __restrict__ shift, const unsigned short* __restrict__ Wt4,
    const float* __restrict__ b4, const int* __restrict__ xy,
    int g, unsigned int* __restrict__ D)
{
    constexpr int K = 256;
    constexpr int NI = CG / 16;
    __shared__ __align__(16) unsigned short As[128 * 40];
    __shared__ __align__(16) unsigned short Bs[CG * 40];
    __shared__ float scs[K], shs[K];
    __shared__ float b4s[CG];
    __shared__ int ids_s[128];
    int t = threadIdx.x;
    int m0 = blockIdx.x * 128, c0 = g * CG;
    for (int i = t; i < K; i += 256) { scs[i] = scale[i]; shs[i] = shift[i]; }
    if (t < CG) b4s[t] = b4[c0 + t];
    if (t < 128) {
        int p = m0 + t;
        ids_s[t] = (p < NPTS) ? (xy[(size_t)p * 2] * GYD + xy[(size_t)p * 2 + 1]) : -1;
    }
    int lane = t & 63, w = t >> 6, quad = lane >> 4, lr = lane & 15;
    f32x4 acc[2][NI];
#pragma unroll
    for (int i = 0; i < 2; ++i)
#pragma unroll
        for (int j = 0; j < NI; ++j) acc[i][j] = (f32x4){0.f, 0.f, 0.f, 0.f};

    for (int kt = 0; kt < K; kt += 32) {
        __syncthreads();
#pragma unroll
        for (int i = 0; i < 2; ++i) {
            int cch = t + i * 256;
            int row = cch >> 2, ko = (cch & 3) * 8;
            int gr = m0 + row;
            bn_stage8(A + (size_t)gr * K + kt + ko, scs, shs, kt + ko,
                      &As[row * 40 + ko], gr < NPTS);
        }
        if constexpr (CG == 64) {
            int n = t >> 2, ko = (t & 3) * 8;
            *(uint4*)&Bs[n * 40 + ko] = *(const uint4*)(Wt4 + (size_t)(c0 + n) * K + kt + ko);
        } else {
            if (t < CG * 4) {
                int n = t >> 2, ko = (t & 3) * 8;
                *(uint4*)&Bs[n * 40 + ko] = *(const uint4*)(Wt4 + (size_t)(c0 + n) * K + kt + ko);
            }
        }
        __syncthreads();
        short8 af[2], bfr[NI];
#pragma unroll
        for (int mi = 0; mi < 2; ++mi)
            af[mi] = *(const short8*)&As[(w * 32 + mi * 16 + lr) * 40 + quad * 8];
#pragma unroll
        for (int ni = 0; ni < NI; ++ni)
            bfr[ni] = *(const short8*)&Bs[(ni * 16 + lr) * 40 + quad * 8];
#pragma unroll
        for (int mi = 0; mi < 2; ++mi)
#pragma unroll
            for (int ni = 0; ni < NI; ++ni)
                acc[mi][ni] = __builtin_amdgcn_mfma_f32_16x16x32_bf16(
                    af[mi], bfr[ni], acc[mi][ni], 0, 0, 0);
    }
#pragma unroll
    for (int ni = 0; ni < NI; ++ni) {
        int col = ni * 16 + lr;
        float bv = b4s[col];
#pragma unroll
        for (int mi = 0; mi < 2; ++mi) {
            int rb = w * 32 + mi * 16 + quad * 4;
#pragma unroll
            for (int r = 0; r < 4; ++r) {
                int id = ids_s[rb + r];
                if (id >= 0)
                    atomicMax(&D[(size_t)id * CG + col], fkey(acc[mi][ni][r] + bv));
            }
        }
    }
}

// ---- accumulate E[cell][32] += funkey(D[cell][:CG]) @ W5[g*CG:(g+1)*CG, :] ----
template<int CG>
__global__ __launch_bounds__(256) void accum_kernel(
    const unsigned int* __restrict__ D, const float* __restrict__ W5,
    int g, float* __restrict__ E)
{
    __shared__ float Ds[64][CG + 1];
    __shared__ float W5s[CG][32];
    int t = threadIdx.x;
    int c0 = blockIdx.x * 64;
    for (int i = t; i < CG * 32; i += 256) {
        int k = i >> 5, c = i & 31;
        W5s[k][c] = W5[(size_t)(g * CG + k) * 32 + c];
    }
    constexpr int QPC = CG / 4;
    for (int i = t; i < 64 * QPC; i += 256) {
        int cell = i / QPC, kq = (i % QPC) * 4;
        uint4 v = *(const uint4*)(D + (size_t)(c0 + cell) * CG + kq);
        Ds[cell][kq + 0] = funkey(v.x);
        Ds[cell][kq + 1] = funkey(v.y);
        Ds[cell][kq + 2] = funkey(v.z);
        Ds[cell][kq + 3] = funkey(v.w);
    }
    __syncthreads();
    int cl = t & 63, og = t >> 6;
    float acc[8] = {};
#pragma unroll 8
    for (int k = 0; k < CG; ++k) {
        float v = Ds[cl][k];
#pragma unroll
        for (int j = 0; j < 8; ++j) acc[j] = fmaf(v, W5s[k][og * 8 + j], acc[j]);
    }
    float* e = E + (size_t)(c0 + cl) * 32 + og * 8;
    float4 e0 = *(float4*)e, e1 = *(float4*)(e + 4);
    e0.x += acc[0]; e0.y += acc[1]; e0.z += acc[2]; e0.w += acc[3];
    e1.x += acc[4]; e1.y += acc[5]; e1.z += acc[6]; e1.w += acc[7];
    *(float4*)e = e0; *(float4*)(e + 4) = e1;
}

// ---- occupancy scatter ----
__global__ __launch_bounds__(256) void occ_kernel(const int* __restrict__ xy,
                                                  unsigned char* __restrict__ occ)
{
    int p = blockIdx.x * 256 + threadIdx.x;
    if (p < NPTS) {
        int id = xy[(size_t)p * 2] * GYD + xy[(size_t)p * 2 + 1];
        occ[id] = 1;
    }
}

// ---- output: out[h][cell] = occ ? relu(E[cell][h] + b5[h]) : 0; zeros for gx>=360 ----
__global__ __launch_bounds__(256) void out_kernel(
    const float* __restrict__ E, const unsigned char* __restrict__ occ,
    const float* __restrict__ b5, float* __restrict__ out)
{
    int t = threadIdx.x;
    int c0 = blockIdx.x * 64;
    int lane = t & 63, hq = t >> 6;
    int cell = c0 + lane;
    if (c0 >= SEGR) {
#pragma unroll
        for (int j = 0; j < 8; ++j)
            out[(size_t)(hq * 8 + j) * NSEG + cell] = 0.f;
        return;
    }
    bool oc = occ[cell] != 0;
    float4 e0 = *(const float4*)(E + (size_t)cell * 32 + hq * 8);
    float4 e1 = *(const float4*)(E + (size_t)cell * 32 + hq * 8 + 4);
    float r[8] = {e0.x, e0.y, e0.z, e0.w, e1.x, e1.y, e1.z, e1.w};
#pragma unroll
    for (int j = 0; j < 8; ++j) {
        float v = oc ? fmaxf(r[j] + b5[hq * 8 + j], 0.f) : 0.f;
        out[(size_t)(hq * 8 + j) * NSEG + cell] = v;
    }
}

extern "C" void kernel_launch(void* const* d_in, const int* in_sizes, int n_in,
                              void* d_out, int out_size, void* d_ws, size_t ws_size,
                              hipStream_t stream)
{
    const float* pt_fea = (const float*)d_in[0];
    const int*   xy_ind = (const int*)d_in[1];
    const float* bn0_g  = (const float*)d_in[2];
    const float* bn0_b  = (const float*)d_in[3];
    const float* W1     = (const float*)d_in[4];
    const float* b1     = (const float*)d_in[5];
    const float* bn1_g  = (const float*)d_in[6];
    const float* bn1_b  = (const float*)d_in[7];
    const float* W2     = (const float*)d_in[8];
    const float* b2     = (const float*)d_in[9];
    const float* bn2_g  = (const float*)d_in[10];
    const float* bn2_b  = (const float*)d_in[11];
    const float* W3     = (const float*)d_in[12];
    const float* b3     = (const float*)d_in[13];
    const float* bn3_g  = (const float*)d_in[14];
    const float* bn3_b  = (const float*)d_in[15];
    const float* W4     = (const float*)d_in[16];
    const float* b4     = (const float*)d_in[17];
    const float* W5     = (const float*)d_in[18];
    const float* b5     = (const float*)d_in[19];
    float* out = (float*)d_out;

    // ---- workspace layout ----
    // [0, 61.44M):   y3 bf16; y1 bf16 [0,15.36M) earlier (dead before L3 writes)
    // [61.44M, +Dsz): y2 bf16 (dead after L3) reused as D keys
    // then E (16.59M), then stats(16KB) + Wt2/Wt3/Wt4 bf16 + occ
    const bool big = ws_size >= (size_t)120 * 1024 * 1024;
    const int CG = big ? 64 : 32;
    const size_t oY2 = 61440000;                   // 120000*256*2
    const size_t oD  = 61440000;
    const size_t Dsz = (size_t)SEGR * CG * 4;
    const size_t oE  = oD + Dsz;
    const size_t oS  = oE + (size_t)SEGR * 32 * 4;

    unsigned short* y1 = (unsigned short*)d_ws;
    unsigned short* y2 = (unsigned short*)((char*)d_ws + oY2);
    unsigned short* y3 = (unsigned short*)d_ws;
    unsigned int*   D  = (unsigned int*)((char*)d_ws + oD);
    float*          E  = (float*)((char*)d_ws + oE);
    float*          st = (float*)((char*)d_ws + oS);

    float* s0 = st + 0;     float* q0 = st + 8;
    float* W1p = st + 16;   float* b1p = st + 464;
    float* sum1 = st + 528; float* sq1 = st + 592; float* sc1 = st + 656; float* sh1 = st + 720;
    float* sum2 = st + 784; float* sq2 = st + 912; float* sc2 = st + 1040; float* sh2 = st + 1168;
    float* sum3 = st + 1296; float* sq3 = st + 1552; float* sc3 = st + 1808; float* sh3 = st + 2064;
    unsigned short* Wt2 = (unsigned short*)(st + 4096);       // [128][64]
    unsigned short* Wt3 = Wt2 + 8192;                         // [256][128]
    unsigned short* Wt4 = Wt3 + 32768;                        // [512][256]
    unsigned char*  occ = (unsigned char*)(Wt4 + 131072);

    const int ngroups = 512 / CG;
    const int MB = (NPTS + 127) / 128;   // 938 row-blocks

    // weights identical for both samples: convert once
    wtrans_kernel<<<(64 * 128 + 255) / 256, 256, 0, stream>>>(W2, Wt2, 64, 128);
    wtrans_kernel<<<(128 * 256 + 255) / 256, 256, 0, stream>>>(W3, Wt3, 128, 256);
    wtrans_kernel<<<(256 * 512 + 255) / 256, 256, 0, stream>>>(W4, Wt4, 256, 512);

    for (int b = 0; b < 2; ++b) {
        const float* fea_b = pt_fea + (size_t)b * NPTS * 7;
        const int*   xy_b  = xy_ind + (size_t)b * NPTS * 2;
        float*       out_b = out + (size_t)b * NHD * NSEG;

        (void)hipMemsetAsync(st, 0, 2320 * sizeof(float), stream);
        (void)hipMemsetAsync(occ, 0, SEGR, stream);
        (void)hipMemsetAsync(E, 0, (size_t)SEGR * 32 * sizeof(float), stream);

        bn0_stats_kernel<<<128, 256, 0, stream>>>(fea_b, s0, q0);
        prep0_kernel<<<1, 64, 0, stream>>>(s0, q0, bn0_g, bn0_b, W1, b1, W1p, b1p);
        layer1_kernel<<<NPTS / 64, 256, 0, stream>>>(fea_b, W1p, b1p, y1, sum1, sq1);
        prep_bn_kernel<<<1, 64, 0, stream>>>(sum1, sq1, bn1_g, bn1_b, sc1, sh1, 64);
        gemm_bn_mfma<64, 128><<<dim3(MB, 1), 256, 0, stream>>>(
            y1, sc1, sh1, Wt2, b2, y2, sum2, sq2);
        prep_bn_kernel<<<1, 128, 0, stream>>>(sum2, sq2, bn2_g, bn2_b, sc2, sh2, 128);
        gemm_bn_mfma<128, 256><<<dim3(MB, 2), 256, 0, stream>>>(
            y2, sc2, sh2, Wt3, b3, y3, sum3, sq3);
        prep_bn_kernel<<<1, 256, 0, stream>>>(sum3, sq3, bn3_g, bn3_b, sc3, sh3, 256);
        occ_kernel<<<(NPTS + 255) / 256, 256, 0, stream>>>(xy_b, occ);

        for (int g = 0; g < ngroups; ++g) {
            (void)hipMemsetAsync(D, 0, Dsz, stream);
            if (CG == 64) {
                scatter_mfma<64><<<MB, 256, 0, stream>>>(y3, sc3, sh3, Wt4, b4, xy_b, g, D);
                accum_kernel<64><<<SEGR / 64, 256, 0, stream>>>(D, W5, g, E);
            } else {
                scatter_mfma<32><<<MB, 256, 0, stream>>>(y3, sc3, sh3, Wt4, b4, xy_b, g, D);
                accum_kernel<32><<<SEGR / 64, 256, 0, stream>>>(D, W5, g, E);
            }
        }
        out_kernel<<<NSEG / 64, 256, 0, stream>>>(E, occ, b5, out_b);
    }
}

// Round 4
// 952.245 us; speedup vs baseline: 3.3562x; 1.6370x over previous
//
#include <hip/hip_runtime.h>
#include <cstdint>

#define GXD 480
#define GYD 360
#define NHD 32
#define NPTS 120000
#define MPAD 120064           // NPTS padded to multiple of 128
#define SEGR 129600           // 360*360 possible ids
#define NSEG (GXD*GYD)        // 172800
#define EPSB 1e-5f

using short8 = __attribute__((ext_vector_type(8))) short;   // 8 bf16 in 4 VGPRs
using f32x4  = __attribute__((ext_vector_type(4))) float;   // MFMA accumulator

// ---- bf16 helpers ----
__device__ __forceinline__ float bf2f(unsigned short u) {
    return __uint_as_float(((unsigned int)u) << 16);
}
__device__ __forceinline__ unsigned short f2bf(float f) {
    unsigned int u = __float_as_uint(f);
    u += 0x7fffu + ((u >> 16) & 1u);   // round-to-nearest-even; exact for bf16-representable
    return (unsigned short)(u >> 16);
}

// ---- staging: load 8 bf16, bn(scale,shift)+relu, 16B to LDS (rows always in padded range) ----
__device__ __forceinline__ void bn_stage8(const unsigned short* gp, const float* scs,
                                          const float* shs, int kbase, unsigned short* lp)
{
    uint4 raw = *(const uint4*)gp;
    unsigned int wds[4] = {raw.x, raw.y, raw.z, raw.w};
    unsigned int ow[4];
#pragma unroll
    for (int q = 0; q < 4; ++q) {
        float lo = bf2f((unsigned short)(wds[q] & 0xffffu));
        float hi = bf2f((unsigned short)(wds[q] >> 16));
        lo = fmaxf(fmaf(lo, scs[kbase + 2*q + 0], shs[kbase + 2*q + 0]), 0.f);
        hi = fmaxf(fmaf(hi, scs[kbase + 2*q + 1], shs[kbase + 2*q + 1]), 0.f);
        ow[q] = (unsigned int)f2bf(lo) | ((unsigned int)f2bf(hi) << 16);
    }
    *(uint4*)lp = make_uint4(ow[0], ow[1], ow[2], ow[3]);
}

// ---- bn0 stats ----
__global__ __launch_bounds__(256) void bn0_stats_kernel(
    const float* __restrict__ fea, float* __restrict__ s0, float* __restrict__ q0)
{
    float s[7] = {0,0,0,0,0,0,0}, q[7] = {0,0,0,0,0,0,0};
    for (int p = blockIdx.x * 256 + threadIdx.x; p < NPTS; p += gridDim.x * 256) {
        const float* r = fea + (size_t)p * 7;
#pragma unroll
        for (int f = 0; f < 7; ++f) { float v = r[f]; s[f] += v; q[f] += v * v; }
    }
    __shared__ float red[256];
    int t = threadIdx.x;
#pragma unroll
    for (int f = 0; f < 7; ++f) {
        red[t] = s[f]; __syncthreads();
        for (int o = 128; o > 0; o >>= 1) {
            if (t < o) red[t] += red[t + o];
            __syncthreads();
        }
        if (t == 0) atomicAdd(&s0[f], red[0]);
        __syncthreads();
        red[t] = q[f]; __syncthreads();
        for (int o = 128; o > 0; o >>= 1) {
            if (t < o) red[t] += red[t + o];
            __syncthreads();
        }
        if (t == 0) atomicAdd(&q0[f], red[0]);
        __syncthreads();
    }
}

// ---- fold bn0 into W1 ----
__global__ void prep0_kernel(const float* __restrict__ s0, const float* __restrict__ q0,
                             const float* __restrict__ g0, const float* __restrict__ b0,
                             const float* __restrict__ W1, const float* __restrict__ b1,
                             float* __restrict__ W1p, float* __restrict__ b1p)
{
    __shared__ float sc[7], sh[7];
    int t = threadIdx.x;
    if (t < 7) {
        float m = s0[t] / (float)NPTS;
        float v = q0[t] / (float)NPTS - m * m;
        float inv = 1.0f / sqrtf(fmaxf(v, 0.f) + EPSB);
        sc[t] = g0[t] * inv;
        sh[t] = b0[t] - m * g0[t] * inv;
    }
    __syncthreads();
    if (t < 64) {
        float acc = b1[t];
#pragma unroll
        for (int f = 0; f < 7; ++f) {
            W1p[f * 64 + t] = W1[f * 64 + t] * sc[f];
            acc += sh[f] * W1[f * 64 + t];
        }
        b1p[t] = acc;
    }
}

__global__ void prep_bn_kernel(const float* __restrict__ sum, const float* __restrict__ sq,
                               const float* __restrict__ g, const float* __restrict__ b,
                               float* __restrict__ sc, float* __restrict__ sh, int C)
{
    int c = blockIdx.x * blockDim.x + threadIdx.x;
    if (c < C) {
        float m = sum[c] / (float)NPTS;
        float v = sq[c] / (float)NPTS - m * m;
        float inv = 1.0f / sqrtf(fmaxf(v, 0.f) + EPSB);
        sc[c] = g[c] * inv;
        sh[c] = b[c] - m * g[c] * inv;
    }
}

// ---- weight transpose+cast: Wt[n][k] = bf16(W[k][n]) ----
__global__ __launch_bounds__(256) void wtrans_kernel(const float* __restrict__ W,
                                                     unsigned short* __restrict__ Wt,
                                                     int K, int N)
{
    int i = blockIdx.x * 256 + threadIdx.x;
    if (i < K * N) {
        int k = i / N, n = i % N;
        Wt[(size_t)n * K + k] = f2bf(W[i]);
    }
}

// ---- layer 1: y1(bf16) = fea @ W1' + b1' (K=7, Nc=64) + fp32 col stats ----
__global__ __launch_bounds__(256) void layer1_kernel(
    const float* __restrict__ fea, const float* __restrict__ W1p, const float* __restrict__ b1p,
    unsigned short* __restrict__ y1, float* __restrict__ sum1, float* __restrict__ sq1)
{
    __shared__ float Wl[448], bl[64], feaL[448];
    __shared__ float red[4][64];
    int t = threadIdx.x;
    int p0 = blockIdx.x * 64;
    for (int i = t; i < 448; i += 256) { Wl[i] = W1p[i]; feaL[i] = fea[(size_t)p0 * 7 + i]; }
    if (t < 64) bl[t] = b1p[t];
    __syncthreads();
    int c = t & 63, pr = t >> 6;
    float s = 0.f, q = 0.f;
#pragma unroll
    for (int it = 0; it < 16; ++it) {
        int pl = it * 4 + pr;
        float v = bl[c];
#pragma unroll
        for (int f = 0; f < 7; ++f) v = fmaf(feaL[pl * 7 + f], Wl[f * 64 + c], v);
        y1[(size_t)(p0 + pl) * 64 + c] = f2bf(v);
        s += v; q += v * v;
    }
    red[pr][c] = s; __syncthreads();
    if (t < 64) atomicAdd(&sum1[c], red[0][c] + red[1][c] + red[2][c] + red[3][c]);
    __syncthreads();
    red[pr][c] = q; __syncthreads();
    if (t < 64) atomicAdd(&sq1[c], red[0][c] + red[1][c] + red[2][c] + red[3][c]);
}

// ---- MFMA GEMM: Y(bf16, padded M) = relu(A*sc+sh) @ Wt^T + bias (+optional col stats) ----
// 128x128 tile, 4 waves 2x2, each 64x64 via 4x4 mfma_16x16x32_bf16.
// Epilogue stages C through LDS -> uint4 coalesced stores (full cache lines).
template<int K, int NC, bool STATS>
__global__ __launch_bounds__(256) void gemm_bn_mfma(
    const unsigned short* __restrict__ A, const float* __restrict__ scale,
    const float* __restrict__ shift, const unsigned short* __restrict__ Wt,
    const float* __restrict__ bias, unsigned short* __restrict__ Y,
    float* __restrict__ osum, float* __restrict__ osq)
{
    __shared__ __align__(16) unsigned short lds[128 * 136];  // C-stage; As/Bs overlap
    unsigned short* As = lds;                 // 128*40
    unsigned short* Bs = lds + 128 * 40;      // 128*40
    __shared__ float scs[K], shs[K];
    __shared__ float bcols[128];
    __shared__ float colsum[128], colsq[128];
    int t = threadIdx.x;
    int m0 = blockIdx.x * 128, c0 = blockIdx.y * 128;
    for (int i = t; i < K; i += 256) { scs[i] = scale[i]; shs[i] = shift[i]; }
    if (t < 128) {
        bcols[t] = bias[c0 + t];
        if (STATS) { colsum[t] = 0.f; colsq[t] = 0.f; }
    }
    int lane = t & 63, w = t >> 6, quad = lane >> 4, lr = lane & 15;
    int wr = w >> 1, wc = w & 1;
    f32x4 acc[4][4];
#pragma unroll
    for (int i = 0; i < 4; ++i)
#pragma unroll
        for (int j = 0; j < 4; ++j) acc[i][j] = (f32x4){0.f, 0.f, 0.f, 0.f};

    for (int kt = 0; kt < K; kt += 32) {
        __syncthreads();
#pragma unroll
        for (int i = 0; i < 2; ++i) {          // A tile: 128 rows x 32 k
            int cch = t + i * 256;
            int row = cch >> 2, ko = (cch & 3) * 8;
            bn_stage8(A + (size_t)(m0 + row) * K + kt + ko, scs, shs, kt + ko,
                      &As[row * 40 + ko]);
        }
#pragma unroll
        for (int i = 0; i < 2; ++i) {          // B tile: 128 n x 32 k
            int cch = t + i * 256;
            int n = cch >> 2, ko = (cch & 3) * 8;
            *(uint4*)&Bs[n * 40 + ko] = *(const uint4*)(Wt + (size_t)(c0 + n) * K + kt + ko);
        }
        __syncthreads();
        short8 af[4], bfr[4];
#pragma unroll
        for (int mi = 0; mi < 4; ++mi)
            af[mi] = *(const short8*)&As[(wr * 64 + mi * 16 + lr) * 40 + quad * 8];
#pragma unroll
        for (int ni = 0; ni < 4; ++ni)
            bfr[ni] = *(const short8*)&Bs[(wc * 64 + ni * 16 + lr) * 40 + quad * 8];
#pragma unroll
        for (int mi = 0; mi < 4; ++mi)
#pragma unroll
            for (int ni = 0; ni < 4; ++ni)
                acc[mi][ni] = __builtin_amdgcn_mfma_f32_16x16x32_bf16(
                    af[mi], bfr[ni], acc[mi][ni], 0, 0, 0);
    }
    __syncthreads();   // all frag reads done; reuse lds as C-stage [128][136]
    // C/D layout: col=lane&15, row=quad*4+reg
#pragma unroll
    for (int ni = 0; ni < 4; ++ni) {
        int col = wc * 64 + ni * 16 + lr;
        float bv = bcols[col];
        float s = 0.f, q = 0.f;
#pragma unroll
        for (int mi = 0; mi < 4; ++mi) {
            int rb = wr * 64 + mi * 16 + quad * 4;
#pragma unroll
            for (int r = 0; r < 4; ++r) {
                float v = acc[mi][ni][r] + bv;
                lds[(rb + r) * 136 + col] = f2bf(v);
                if (STATS && (m0 + rb + r) < NPTS) { s += v; q += v * v; }
            }
        }
        if (STATS) {
            atomicAdd(&colsum[col], s);
            atomicAdd(&colsq[col], q);
        }
    }
    __syncthreads();
#pragma unroll
    for (int i = 0; i < 8; ++i) {              // 128x128 bf16 tile, full-line stores
        int idx = i * 256 + t;
        int row = idx >> 4, colq = (idx & 15) * 8;
        *(uint4*)(Y + (size_t)(m0 + row) * NC + c0 + colq) = *(const uint4*)&lds[row * 136 + colq];
    }
    if (STATS && t < 128) {
        atomicAdd(&osum[c0 + t], colsum[t]);
        atomicAdd(&osq[c0 + t], colsq[t]);
    }
}

// ---- sort machinery: histogram, 3-phase exclusive scan, index scatter ----
__global__ __launch_bounds__(256) void hist_kernel(const int* __restrict__ xy,
                                                   int* __restrict__ cnt)
{
    int p = blockIdx.x * 256 + threadIdx.x;
    if (p < NPTS) {
        int id = xy[(size_t)p * 2] * GYD + xy[(size_t)p * 2 + 1];
        atomicAdd(&cnt[id], 1);
    }
}

__global__ __launch_bounds__(256) void scanA_kernel(const int* __restrict__ cnt,
                                                    int* __restrict__ csum)
{
    __shared__ int red[256];
    int t = threadIdx.x, base = blockIdx.x * 2048;
    int s = 0;
    for (int i = t; i < 2048; i += 256) {
        int idx = base + i;
        if (idx < SEGR) s += cnt[idx];
    }
    red[t] = s; __syncthreads();
    for (int o = 128; o > 0; o >>= 1) { if (t < o) red[t] += red[t + o]; __syncthreads(); }
    if (t == 0) csum[blockIdx.x] = red[0];
}

__global__ void scanB_kernel(int* __restrict__ csum, int* __restrict__ offs)
{
    if (threadIdx.x == 0) {
        int run = 0;
        for (int i = 0; i < 64; ++i) { int v = csum[i]; csum[i] = run; run += v; }
        offs[SEGR] = run;
    }
}

__global__ __launch_bounds__(256) void scanC_kernel(const int* __restrict__ cnt,
                                                    const int* __restrict__ csum,
                                                    int* __restrict__ offs,
                                                    int* __restrict__ cursor)
{
    __shared__ int red[256];
    int t = threadIdx.x, base = blockIdx.x * 2048;
    int v[8]; int s = 0;
#pragma unroll
    for (int i = 0; i < 8; ++i) {
        int idx = base + t * 8 + i;
        v[i] = (idx < SEGR) ? cnt[idx] : 0;
        s += v[i];
    }
    red[t] = s; __syncthreads();
    for (int o = 1; o < 256; o <<= 1) {        // Hillis-Steele inclusive scan
        int x = (t >= o) ? red[t - o] : 0;
        __syncthreads();
        red[t] += x;
        __syncthreads();
    }
    int run = red[t] - s + csum[blockIdx.x];
#pragma unroll
    for (int i = 0; i < 8; ++i) {
        int idx = base + t * 8 + i;
        if (idx < SEGR) { offs[idx] = run; cursor[idx] = run; }
        run += v[i];
    }
}

__global__ __launch_bounds__(256) void scatter_idx_kernel(const int* __restrict__ xy,
                                                          int* __restrict__ cursor,
                                                          int* __restrict__ order)
{
    int p = blockIdx.x * 256 + threadIdx.x;
    if (p < NPTS) {
        int id = xy[(size_t)p * 2] * GYD + xy[(size_t)p * 2 + 1];
        int pos = atomicAdd(&cursor[id], 1);
        order[pos] = p;
    }
}

// ---- fused gather-segmax + partial L5: E[cell][32] (+)= max_pts(y4g) @ W5[g-slice] ----
// block = 64 cells; 4 threads/cell each covering 32 of the 128 group cols
__global__ __launch_bounds__(256) void segmax_l5_kernel(
    const unsigned short* __restrict__ y4g, const unsigned short* __restrict__ Wt5,
    const int* __restrict__ offs, const int* __restrict__ order,
    int g, float* __restrict__ E)
{
    __shared__ __align__(16) unsigned short seg[64 * 136];
    __shared__ __align__(16) unsigned short w5s[32 * 136];
    __shared__ int offs_s[65];
    int t = threadIdx.x;
    int c0 = blockIdx.x * 64;
    if (t < 65) offs_s[t] = offs[c0 + t];
    {   // stage Wt5[n=0..31][k = g*128 .. +128]
        int n = t >> 3, ko = (t & 7) * 16;
        *(uint4*)&w5s[n * 136 + ko]     = *(const uint4*)(Wt5 + (size_t)n * 512 + g * 128 + ko);
        *(uint4*)&w5s[n * 136 + ko + 8] = *(const uint4*)(Wt5 + (size_t)n * 512 + g * 128 + ko + 8);
    }
    __syncthreads();
    int cell = t >> 2, q = t & 3;
    float mx[32];
#pragma unroll
    for (int i = 0; i < 32; ++i) mx[i] = -3.0e38f;
    int jb = offs_s[cell], je = offs_s[cell + 1];
    for (int j = jb; j < je; ++j) {
        int p = order[j];
        const uint4* rp = (const uint4*)(y4g + (size_t)p * 128 + q * 32);
#pragma unroll
        for (int u = 0; u < 4; ++u) {
            uint4 vv = rp[u];
            unsigned int wv[4] = {vv.x, vv.y, vv.z, vv.w};
#pragma unroll
            for (int k2 = 0; k2 < 4; ++k2) {
                int idx = u * 8 + k2 * 2;
                mx[idx]     = fmaxf(mx[idx],     bf2f((unsigned short)(wv[k2] & 0xffffu)));
                mx[idx + 1] = fmaxf(mx[idx + 1], bf2f((unsigned short)(wv[k2] >> 16)));
            }
        }
    }
    bool empty = (jb == je);
#pragma unroll
    for (int i = 0; i < 16; ++i) {
        float lo = empty ? 0.f : mx[2 * i], hi = empty ? 0.f : mx[2 * i + 1];
        unsigned int pk = (unsigned int)f2bf(lo) | ((unsigned int)f2bf(hi) << 16);
        *(unsigned int*)&seg[cell * 136 + q * 32 + 2 * i] = pk;
    }
    __syncthreads();
    // MFMA: M=64 cells (wave w -> cells w*16..+15), N=32 (2 tiles), K=128 (4 iters)
    int lane = t & 63, w = t >> 6, quad = lane >> 4, lr = lane & 15;
    f32x4 acc[2];
    acc[0] = (f32x4){0.f, 0.f, 0.f, 0.f};
    acc[1] = (f32x4){0.f, 0.f, 0.f, 0.f};
#pragma unroll
    for (int kt = 0; kt < 4; ++kt) {
        short8 af = *(const short8*)&seg[(w * 16 + lr) * 136 + kt * 32 + quad * 8];
#pragma unroll
        for (int ni = 0; ni < 2; ++ni) {
            short8 bfr = *(const short8*)&w5s[(ni * 16 + lr) * 136 + kt * 32 + quad * 8];
            acc[ni] = __builtin_amdgcn_mfma_f32_16x16x32_bf16(af, bfr, acc[ni], 0, 0, 0);
        }
    }
#pragma unroll
    for (int ni = 0; ni < 2; ++ni) {
        int h = ni * 16 + lr;
#pragma unroll
        for (int r = 0; r < 4; ++r) {
            int cr = w * 16 + quad * 4 + r;
            float* ep = E + (size_t)(c0 + cr) * 32 + h;
            float v = acc[ni][r];
            if (g > 0) v += *ep;
            *ep = v;
        }
    }
}

// ---- output: out[h][cell] = occ ? relu(E[cell][h] + b5[h]) : 0 ----
__global__ __launch_bounds__(256) void out_kernel(
    const float* __restrict__ E, const int* __restrict__ cnt,
    const float* __restrict__ b5, float* __restrict__ out)
{
    int t = threadIdx.x;
    int c0 = blockIdx.x * 64;
    int lane = t & 63, hq = t >> 6;
    int cell = c0 + lane;
    if (c0 >= SEGR) {
#pragma unroll
        for (int j = 0; j < 8; ++j)
            out[(size_t)(hq * 8 + j) * NSEG + cell] = 0.f;
        return;
    }
    bool oc = cnt[cell] > 0;
    float4 e0 = *(const float4*)(E + (size_t)cell * 32 + hq * 8);
    float4 e1 = *(const float4*)(E + (size_t)cell * 32 + hq * 8 + 4);
    float r[8] = {e0.x, e0.y, e0.z, e0.w, e1.x, e1.y, e1.z, e1.w};
#pragma unroll
    for (int j = 0; j < 8; ++j) {
        float v = oc ? fmaxf(r[j] + b5[hq * 8 + j], 0.f) : 0.f;
        out[(size_t)(hq * 8 + j) * NSEG + cell] = v;
    }
}

extern "C" void kernel_launch(void* const* d_in, const int* in_sizes, int n_in,
                              void* d_out, int out_size, void* d_ws, size_t ws_size,
                              hipStream_t stream)
{
    const float* pt_fea = (const float*)d_in[0];
    const int*   xy_ind = (const int*)d_in[1];
    const float* bn0_g  = (const float*)d_in[2];
    const float* bn0_b  = (const float*)d_in[3];
    const float* W1     = (const float*)d_in[4];
    const float* b1     = (const float*)d_in[5];
    const float* bn1_g  = (const float*)d_in[6];
    const float* bn1_b  = (const float*)d_in[7];
    const float* W2     = (const float*)d_in[8];
    const float* b2     = (const float*)d_in[9];
    const float* bn2_g  = (const float*)d_in[10];
    const float* bn2_b  = (const float*)d_in[11];
    const float* W3     = (const float*)d_in[12];
    const float* b3     = (const float*)d_in[13];
    const float* bn3_g  = (const float*)d_in[14];
    const float* bn3_b  = (const float*)d_in[15];
    const float* W4     = (const float*)d_in[16];
    const float* b4     = (const float*)d_in[17];
    const float* W5     = (const float*)d_in[18];
    const float* b5     = (const float*)d_in[19];
    float* out = (float*)d_out;

    // ---- workspace layout (~111.2 MB; R3 proved ws >= ~111.7 MB) ----
    // [0, 61.47M):        y3 bf16 [MPAD][256]; y1 bf16 [MPAD][64] lives here earlier
    // [61.47M, 92.21M):   y2 bf16 [MPAD][128]; reused as y4g [MPAD][128] after L3
    // [92.21M, 108.80M):  E fp32 [SEGR][32]
    // then cnt/offs/cursor/order/csum/stats/Wt2/Wt3/Wt4/Wt5
    const size_t oY2   = 61472768;                 // MPAD*256*2
    const size_t oE    = oY2 + (size_t)MPAD * 128 * 2;     //  92209152
    const size_t oCnt  = oE + (size_t)SEGR * 32 * 4;       // 108797952
    const size_t oOffs = oCnt + 518400;
    const size_t oCur  = oOffs + 518528;
    const size_t oOrd  = oCur + 518400;
    const size_t oCsum = oOrd + 480000;
    const size_t oSt   = oCsum + 512;
    const size_t oWt2  = oSt + 16384;
    const size_t oWt3  = oWt2 + 16384;
    const size_t oWt4  = oWt3 + 65536;
    const size_t oWt5  = oWt4 + 262144;            // end = oWt5 + 32768 ≈ 111.2 MB

    unsigned short* y1   = (unsigned short*)d_ws;
    unsigned short* y3   = (unsigned short*)d_ws;
    unsigned short* y2   = (unsigned short*)((char*)d_ws + oY2);
    unsigned short* y4g  = (unsigned short*)((char*)d_ws + oY2);
    float*          E    = (float*)((char*)d_ws + oE);
    int*            cnt  = (int*)((char*)d_ws + oCnt);
    int*            offs = (int*)((char*)d_ws + oOffs);
    int*            cur  = (int*)((char*)d_ws + oCur);
    int*            ord  = (int*)((char*)d_ws + oOrd);
    int*            csum = (int*)((char*)d_ws + oCsum);
    float*          st   = (float*)((char*)d_ws + oSt);
    unsigned short* Wt2  = (unsigned short*)((char*)d_ws + oWt2);
    unsigned short* Wt3  = (unsigned short*)((char*)d_ws + oWt3);
    unsigned short* Wt4  = (unsigned short*)((char*)d_ws + oWt4);
    unsigned short* Wt5  = (unsigned short*)((char*)d_ws + oWt5);

    float* s0 = st + 0;     float* q0 = st + 8;
    float* W1p = st + 16;   float* b1p = st + 464;
    float* sum1 = st + 528; float* sq1 = st + 592; float* sc1 = st + 656; float* sh1 = st + 720;
    float* sum2 = st + 784; float* sq2 = st + 912; float* sc2 = st + 1040; float* sh2 = st + 1168;
    float* sum3 = st + 1296; float* sq3 = st + 1552; float* sc3 = st + 1808; float* sh3 = st + 2064;

    const int MB = MPAD / 128;   // 938

    // weights identical for both samples: convert once
    wtrans_kernel<<<(64 * 128 + 255) / 256, 256, 0, stream>>>(W2, Wt2, 64, 128);
    wtrans_kernel<<<(128 * 256 + 255) / 256, 256, 0, stream>>>(W3, Wt3, 128, 256);
    wtrans_kernel<<<(256 * 512 + 255) / 256, 256, 0, stream>>>(W4, Wt4, 256, 512);
    wtrans_kernel<<<(512 * 32 + 255) / 256, 256, 0, stream>>>(W5, Wt5, 512, 32);

    for (int b = 0; b < 2; ++b) {
        const float* fea_b = pt_fea + (size_t)b * NPTS * 7;
        const int*   xy_b  = xy_ind + (size_t)b * NPTS * 2;
        float*       out_b = out + (size_t)b * NHD * NSEG;

        (void)hipMemsetAsync(st, 0, 2320 * sizeof(float), stream);
        (void)hipMemsetAsync(cnt, 0, (size_t)SEGR * 4, stream);

        bn0_stats_kernel<<<128, 256, 0, stream>>>(fea_b, s0, q0);
        prep0_kernel<<<1, 64, 0, stream>>>(s0, q0, bn0_g, bn0_b, W1, b1, W1p, b1p);
        layer1_kernel<<<NPTS / 64, 256, 0, stream>>>(fea_b, W1p, b1p, y1, sum1, sq1);
        prep_bn_kernel<<<1, 64, 0, stream>>>(sum1, sq1, bn1_g, bn1_b, sc1, sh1, 64);
        gemm_bn_mfma<64, 128, true><<<dim3(MB, 1), 256, 0, stream>>>(
            y1, sc1, sh1, Wt2, b2, y2, sum2, sq2);
        prep_bn_kernel<<<1, 128, 0, stream>>>(sum2, sq2, bn2_g, bn2_b, sc2, sh2, 128);
        gemm_bn_mfma<128, 256, true><<<dim3(MB, 2), 256, 0, stream>>>(
            y2, sc2, sh2, Wt3, b3, y3, sum3, sq3);
        prep_bn_kernel<<<1, 256, 0, stream>>>(sum3, sq3, bn3_g, bn3_b, sc3, sh3, 256);

        // counting sort of points by cell id
        hist_kernel<<<(NPTS + 255) / 256, 256, 0, stream>>>(xy_b, cnt);
        scanA_kernel<<<64, 256, 0, stream>>>(cnt, csum);
        scanB_kernel<<<1, 64, 0, stream>>>(csum, offs);
        scanC_kernel<<<64, 256, 0, stream>>>(cnt, csum, offs, cur);
        scatter_idx_kernel<<<(NPTS + 255) / 256, 256, 0, stream>>>(xy_b, cur, ord);

        // L4 + segmax + L5 in 4 column groups of 128
        for (int g = 0; g < 4; ++g) {
            gemm_bn_mfma<256, 128, false><<<dim3(MB, 1), 256, 0, stream>>>(
                y3, sc3, sh3, Wt4 + (size_t)g * 128 * 256, b4 + g * 128, y4g,
                nullptr, nullptr);
            segmax_l5_kernel<<<SEGR / 64, 256, 0, stream>>>(y4g, Wt5, offs, ord, g, E);
        }
        out_kernel<<<NSEG / 64, 256, 0, stream>>>(E, cnt, b5, out_b);
    }
}